// Round 1
// baseline (5751.907 us; speedup 1.0000x reference)
//
#include <hip/hip_runtime.h>

// Problem sizes (fixed)
#define BB 512
#define TT 256
#define II 256
#define HH 512
// K = II + HH = 768 ; 4H = 2048

typedef __attribute__((ext_vector_type(8))) short bf16x8;   // 4 VGPRs (8 bf16)
typedef __attribute__((ext_vector_type(4))) float f32x4;    // 16x16 accumulator

__device__ __forceinline__ unsigned short f2bf(float f) {
  union { float f; unsigned u; } v; v.f = f;
  unsigned r = v.u + 0x7fffu + ((v.u >> 16) & 1u);   // RNE
  return (unsigned short)(r >> 16);
}

// -------- workspace layout (bytes) --------
// [0,4096)                : group barrier counters (zeroed every call)
// [4096, 4096+2*524288)   : hswz double buffer (h in A-frag swizzle, zeroed)
// [OFF_XSWZ, +64MB)       : x in A-frag swizzle (bf16); later reused for 'a' (fp32, 16MB)
// [OFF_HIST, +128MB)      : lstm_out history (bf16, [B*T][H])
#define OFF_CNT   0
#define OFF_HSWZ  4096
#define OFF_XSWZ  1052672ULL
#define OFF_HIST  68161536ULL
#define ZERO_WORDS 263168   // (4096 + 2*524288)/4

__global__ void zero_k(unsigned* __restrict__ p, int n) {
  int i = blockIdx.x * blockDim.x + threadIdx.x;
  if (i < n) p[i] = 0u;
}

// Swizzle x[b][t][k] (fp32) -> xswz[t][kc][rc][lane][8] (bf16), A-frag order.
// element: b = rc*16 + (lane&15) ; k = kc*32 + (lane>>4)*8 + j
__global__ void prep_x(const float* __restrict__ x, unsigned char* __restrict__ ws) {
  unsigned idx = blockIdx.x * 256u + threadIdx.x;   // 16384*256 = 4,194,304 exact
  int lane = idx & 63;
  int rc   = (idx >> 6) & 31;
  int kc   = (idx >> 11) & 7;
  int t    = idx >> 14;
  int b  = rc * 16 + (lane & 15);
  int k0 = kc * 32 + ((lane >> 4) & 3) * 8;
  const float* s = x + ((size_t)b * TT + t) * II + k0;
  union { unsigned short h[8]; uint4 v; } pk;
#pragma unroll
  for (int j = 0; j < 8; ++j) pk.h[j] = f2bf(s[j]);
  ((uint4*)(ws + OFF_XSWZ))[idx] = pk.v;
}

// Persistent fused LSTM. 256 blocks x 256 threads, all co-resident.
// group = blockIdx&7 (XCD-affine under round-robin), member m = blockIdx>>3.
// Group owns batch rows [group*64, +64). Member owns h-cols [m*16,+16)
// i.e. gate cols nt*512 + m*16 + [0,16) for nt = gate = 0..3 (i,f,g,o).
__global__ __launch_bounds__(256, 1) void lstm_persist(
    const float* __restrict__ Wih, const float* __restrict__ Whh,
    const float* __restrict__ bih, const float* __restrict__ bhh,
    unsigned char* __restrict__ ws)
{
  const int gid = blockIdx.x;
  const int group = gid & 7;
  const int m = gid >> 3;
  const int tid = threadIdx.x;
  const int wv = tid >> 6, lane = tid & 63;
  const int mb = wv & 1, kh = wv >> 1;       // wave = (m-half, K-half)
  const int lq = lane >> 4, ln = lane & 15;  // quad, low nibble

  int* cnt = (int*)(ws + OFF_CNT);
  unsigned char* xswz  = ws + OFF_XSWZ;
  unsigned char* hswz0 = ws + OFF_HSWZ;
  unsigned char* hswz1 = ws + OFF_HSWZ + 524288;
  unsigned char* hist  = ws + OFF_HIST;

  // ---- W-slice preload into VGPRs: Wf[kk][nt], K-half per wave, no dup ----
  bf16x8 Wf[12][4];
#pragma unroll
  for (int kk = 0; kk < 12; ++kk) {
    const int kb = kh * 384 + kk * 32 + lq * 8;   // never straddles 256
#pragma unroll
    for (int nt = 0; nt < 4; ++nt) {
      const int gcol = nt * 512 + m * 16 + ln;
      const float* s = (kb < 256) ? (Wih + (size_t)gcol * 256 + kb)
                                  : (Whh + (size_t)gcol * 512 + (kb - 256));
      bf16x8 w;
#pragma unroll
      for (int j = 0; j < 8; ++j) w[j] = (short)f2bf(s[j]);
      Wf[kk][nt] = w;
    }
  }

  __shared__ float g_s[64 * 69];   // gate preacts [row][gate*16+jl], padded stride
  __shared__ float c_s[64 * 17];   // cell state
  __shared__ float h_s[64 * 17];   // new h (fp32 staging)
  __shared__ float bias_s[64];

  for (int i = tid; i < 64 * 17; i += 256) c_s[i] = 0.f;
  if (tid < 64) {
    int gcol = (tid >> 4) * 512 + m * 16 + (tid & 15);
    bias_s[tid] = bih[gcol] + bhh[gcol];
  }
  __syncthreads();

  const int rcb = group * 4 + mb * 2;   // row-chunk base (16-row chunks)
  const int row_cu = tid & 63;          // cell-update row
  const int jq = tid >> 6;              // cell-update jl group (4 cols)
  const f32x4 zero4 = {0.f, 0.f, 0.f, 0.f};

#pragma unroll 1
  for (int t = 0; t < 256; ++t) {
    unsigned char* hrd = (t & 1) ? hswz1 : hswz0;
    unsigned char* hwr = (t & 1) ? hswz0 : hswz1;

    f32x4 acc[2][4];
#pragma unroll
    for (int mt = 0; mt < 2; ++mt)
#pragma unroll
      for (int nt = 0; nt < 4; ++nt) acc[mt][nt] = zero4;

    // ---- K-loop: A-frags straight from swizzled global (L2), W from VGPRs ----
#pragma unroll
    for (int kk = 0; kk < 12; ++kk) {
      const int kg = kh * 384 + kk * 32;
      const unsigned char* base;
      if (kg < 256) base = xswz + (size_t)(t * 8 + (kg >> 5)) * 32768u;
      else          base = hrd + (size_t)((kg - 256) >> 5) * 32768u;
      bf16x8 a0 = *(const bf16x8*)(base + (((rcb + 0) * 64 + lane) * 16));
      bf16x8 a1 = *(const bf16x8*)(base + (((rcb + 1) * 64 + lane) * 16));
#pragma unroll
      for (int nt = 0; nt < 4; ++nt) {
        acc[0][nt] = __builtin_amdgcn_mfma_f32_16x16x32_bf16(a0, Wf[kk][nt], acc[0][nt], 0, 0, 0);
        acc[1][nt] = __builtin_amdgcn_mfma_f32_16x16x32_bf16(a1, Wf[kk][nt], acc[1][nt], 0, 0, 0);
      }
    }

    // ---- split-K reduce via LDS (C/D layout: col=ln, row=lq*4+r) ----
    if (kh == 1) {
#pragma unroll
      for (int mt = 0; mt < 2; ++mt)
#pragma unroll
        for (int nt = 0; nt < 4; ++nt)
#pragma unroll
          for (int r = 0; r < 4; ++r)
            g_s[(mb * 32 + mt * 16 + lq * 4 + r) * 69 + nt * 16 + ln] = acc[mt][nt][r];
    }
    __syncthreads();
    if (kh == 0) {
#pragma unroll
      for (int mt = 0; mt < 2; ++mt)
#pragma unroll
        for (int nt = 0; nt < 4; ++nt)
#pragma unroll
          for (int r = 0; r < 4; ++r) {
            int ix = (mb * 32 + mt * 16 + lq * 4 + r) * 69 + nt * 16 + ln;
            g_s[ix] += acc[mt][nt][r];
          }
    }
    __syncthreads();

    // ---- cell update: 4 cells per thread (row, jl=jq*4+jj) ----
    {
      unsigned short hp0, hp1, hp2, hp3;
      float hv[4];
#pragma unroll
      for (int jj = 0; jj < 4; ++jj) {
        int jl = jq * 4 + jj;
        float gi = g_s[row_cu * 69 + jl]      + bias_s[jl];
        float gf = g_s[row_cu * 69 + 16 + jl] + bias_s[16 + jl];
        float gg = g_s[row_cu * 69 + 32 + jl] + bias_s[32 + jl];
        float go = g_s[row_cu * 69 + 48 + jl] + bias_s[48 + jl];
        float iv = 1.f / (1.f + __expf(-gi));
        float fv = 1.f / (1.f + __expf(-gf));
        float gv = 1.f - 2.f / (__expf(2.f * gg) + 1.f);
        float ov = 1.f / (1.f + __expf(-go));
        float cv = fv * c_s[row_cu * 17 + jl] + iv * gv;
        c_s[row_cu * 17 + jl] = cv;
        float h = ov * (1.f - 2.f / (__expf(2.f * cv) + 1.f));
        h_s[row_cu * 17 + jl] = h;
        hv[jj] = h;
      }
      hp0 = f2bf(hv[0]); hp1 = f2bf(hv[1]); hp2 = f2bf(hv[2]); hp3 = f2bf(hv[3]);
      int b = group * 64 + row_cu;
      ushort4 hq = make_ushort4(hp0, hp1, hp2, hp3);
      *(ushort4*)(hist + ((size_t)(b * 256 + t) * 512 + m * 16 + jq * 4) * 2) = hq;
    }
    __syncthreads();

    // ---- publish h slice into hwr in A-frag swizzle (8B per thread) ----
    {
      int rc_l = tid >> 6;                // 0..3 (row chunk)
      int rem = tid & 63;
      int lane_off = rem >> 1;            // 0..31
      int half = rem & 1;
      int l2 = (m & 1) * 32 + lane_off;   // target lane in chunk
      int rowl = rc_l * 16 + (lane_off & 15);
      int jb = (lane_off >> 4) * 8 + half * 4;
      ushort4 pk = make_ushort4(f2bf(h_s[rowl * 17 + jb + 0]),
                                f2bf(h_s[rowl * 17 + jb + 1]),
                                f2bf(h_s[rowl * 17 + jb + 2]),
                                f2bf(h_s[rowl * 17 + jb + 3]));
      size_t off = ((size_t)((m >> 1) * 32 + group * 4 + rc_l) * 64 + l2) * 16 + half * 8;
      *(ushort4*)(hwr + off) = pk;
    }
    __syncthreads();   // drains all publish stores to L2 (vmcnt(0) before s_barrier)

    // ---- per-group device-scope barrier ----
    if (tid == 0) {
      __builtin_amdgcn_fence(__ATOMIC_RELEASE, "agent");  // flush dirty L2 -> coherence point
      __hip_atomic_fetch_add(cnt + group, 1, __ATOMIC_RELAXED, __HIP_MEMORY_SCOPE_AGENT);
      int target = (t + 1) * 32;
      int iter = 0;
      while (__hip_atomic_load(cnt + group, __ATOMIC_RELAXED, __HIP_MEMORY_SCOPE_AGENT) < target
             && iter < (1 << 18)) { ++iter; __builtin_amdgcn_s_sleep(2); }
      __builtin_amdgcn_fence(__ATOMIC_ACQUIRE, "agent");  // invalidate stale caches
    }
    __syncthreads();
  }
}

// Epilogue 1: a[r][0..32) = lstm_hist[r][:] @ fc1_w^T   (r = b*T + t), fp32 out, no bias.
__global__ __launch_bounds__(256) void e1_fc1(
    const float* __restrict__ fc1_w, const unsigned char* __restrict__ hist,
    float* __restrict__ a_out)
{
  const int tid = threadIdx.x, wv = tid >> 6, lane = tid & 63;
  const int lq = lane >> 4, ln = lane & 15;

  bf16x8 Bf[16][2];
#pragma unroll
  for (int kk = 0; kk < 16; ++kk) {
#pragma unroll
    for (int nt = 0; nt < 2; ++nt) {
      const float* s = fc1_w + (size_t)(nt * 16 + ln) * 512 + kk * 32 + lq * 8;
      bf16x8 w;
#pragma unroll
      for (int j = 0; j < 8; ++j) w[j] = (short)f2bf(s[j]);
      Bf[kk][nt] = w;
    }
  }

  const int rbase = blockIdx.x * 128 + wv * 32;
  const f32x4 zero4 = {0.f, 0.f, 0.f, 0.f};
  f32x4 acc[2][2] = {{zero4, zero4}, {zero4, zero4}};
#pragma unroll
  for (int kk = 0; kk < 16; ++kk) {
    bf16x8 a0 = *(const bf16x8*)(hist + ((size_t)(rbase + ln) * 512 + kk * 32 + lq * 8) * 2);
    bf16x8 a1 = *(const bf16x8*)(hist + ((size_t)(rbase + 16 + ln) * 512 + kk * 32 + lq * 8) * 2);
#pragma unroll
    for (int nt = 0; nt < 2; ++nt) {
      acc[0][nt] = __builtin_amdgcn_mfma_f32_16x16x32_bf16(a0, Bf[kk][nt], acc[0][nt], 0, 0, 0);
      acc[1][nt] = __builtin_amdgcn_mfma_f32_16x16x32_bf16(a1, Bf[kk][nt], acc[1][nt], 0, 0, 0);
    }
  }
#pragma unroll
  for (int mt = 0; mt < 2; ++mt)
#pragma unroll
    for (int nt = 0; nt < 2; ++nt)
#pragma unroll
      for (int r = 0; r < 4; ++r) {
        int row = rbase + mt * 16 + lq * 4 + r;
        a_out[(size_t)row * 32 + nt * 16 + ln] = acc[mt][nt][r];
      }
}

// Epilogue 2: per-t BN1 + leaky-relu + fc2 + BN2 + relu. One block per t.
__global__ __launch_bounds__(256) void e2_head(
    const float* __restrict__ a_in, const float* __restrict__ fc1_b,
    const float* __restrict__ fc2_w, const float* __restrict__ fc2_b,
    const float* __restrict__ bn1_g, const float* __restrict__ bn1_b,
    const float* __restrict__ bn2_g, const float* __restrict__ bn2_b,
    float* __restrict__ out)
{
  const int t = blockIdx.x, tid = threadIdx.x;
  __shared__ float fb[32], fw[32];
  __shared__ float red[4][2], red2[4][2];
  if (tid < 32) { fb[tid] = fc1_b[tid]; fw[tid] = fc2_w[tid]; }
  __syncthreads();

  float va[2][32];
  float s1 = 0.f, s2 = 0.f;
#pragma unroll
  for (int rr = 0; rr < 2; ++rr) {
    int b = tid * 2 + rr;
    const float* p = a_in + ((size_t)b * 256 + t) * 32;
#pragma unroll
    for (int o = 0; o < 32; ++o) {
      float v = p[o] + fb[o];
      va[rr][o] = v;
      s1 += v; s2 += v * v;
    }
  }
#pragma unroll
  for (int off = 32; off > 0; off >>= 1) {
    s1 += __shfl_down(s1, off);
    s2 += __shfl_down(s2, off);
  }
  if ((tid & 63) == 0) { red[tid >> 6][0] = s1; red[tid >> 6][1] = s2; }
  __syncthreads();
  float tot1 = red[0][0] + red[1][0] + red[2][0] + red[3][0];
  float tot2 = red[0][1] + red[1][1] + red[2][1] + red[3][1];
  float m1 = tot1 * (1.f / 16384.f);
  float v1 = tot2 * (1.f / 16384.f) - m1 * m1;
  float sc1 = bn1_g[t] * rsqrtf(v1 + 1e-5f);
  float sh1 = bn1_b[t];

  float z[2];
  float zs1 = 0.f, zs2 = 0.f;
#pragma unroll
  for (int rr = 0; rr < 2; ++rr) {
    float acc = fc2_b[0];
#pragma unroll
    for (int o = 0; o < 32; ++o) {
      float av = (va[rr][o] - m1) * sc1 + sh1;
      av = (av > 0.f) ? av : 0.1f * av;
      acc += av * fw[o];
    }
    z[rr] = acc; zs1 += acc; zs2 += acc * acc;
  }
#pragma unroll
  for (int off = 32; off > 0; off >>= 1) {
    zs1 += __shfl_down(zs1, off);
    zs2 += __shfl_down(zs2, off);
  }
  if ((tid & 63) == 0) { red2[tid >> 6][0] = zs1; red2[tid >> 6][1] = zs2; }
  __syncthreads();
  float zt1 = red2[0][0] + red2[1][0] + red2[2][0] + red2[3][0];
  float zt2 = red2[0][1] + red2[1][1] + red2[2][1] + red2[3][1];
  float m2 = zt1 * (1.f / 512.f);
  float v2 = zt2 * (1.f / 512.f) - m2 * m2;
  float sc2 = bn2_g[t] * rsqrtf(v2 + 1e-5f);
  float sh2 = bn2_b[t];
#pragma unroll
  for (int rr = 0; rr < 2; ++rr) {
    int b = tid * 2 + rr;
    float res = (z[rr] - m2) * sc2 + sh2;
    out[(size_t)b * 256 + t] = (res > 0.f) ? res : 0.f;
  }
}

extern "C" void kernel_launch(void* const* d_in, const int* in_sizes, int n_in,
                              void* d_out, int out_size, void* d_ws, size_t ws_size,
                              hipStream_t stream) {
  const float* x    = (const float*)d_in[0];
  const float* Wih  = (const float*)d_in[1];
  const float* Whh  = (const float*)d_in[2];
  const float* bih  = (const float*)d_in[3];
  const float* bhh  = (const float*)d_in[4];
  const float* fc1w = (const float*)d_in[5];
  const float* fc1b = (const float*)d_in[6];
  const float* fc2w = (const float*)d_in[7];
  const float* fc2b = (const float*)d_in[8];
  const float* b1g  = (const float*)d_in[9];
  const float* b1b  = (const float*)d_in[10];
  const float* b2g  = (const float*)d_in[11];
  const float* b2b  = (const float*)d_in[12];
  unsigned char* ws = (unsigned char*)d_ws;
  float* out = (float*)d_out;
  float* a_buf = (float*)(ws + OFF_XSWZ);   // reuses xswz region after persist

  zero_k<<<1028, 256, 0, stream>>>((unsigned*)ws, ZERO_WORDS);
  prep_x<<<16384, 256, 0, stream>>>(x, ws);
  lstm_persist<<<256, 256, 0, stream>>>(Wih, Whh, bih, bhh, ws);
  e1_fc1<<<1024, 256, 0, stream>>>(fc1w, ws + OFF_HIST, a_buf);
  e2_head<<<256, 256, 0, stream>>>(a_buf, fc1b, fc2w, fc2b, b1g, b1b, b2g, b2b, out);
}

// Round 2
// 2135.102 us; speedup vs baseline: 2.6940x; 2.6940x over previous
//
#include <hip/hip_runtime.h>

// Problem sizes (fixed)
#define BB 512
#define TT 256
#define II 256
#define HH 512
// K = II + HH = 768 ; 4H = 2048

typedef __attribute__((ext_vector_type(8))) short bf16x8;   // 4 VGPRs (8 bf16)
typedef __attribute__((ext_vector_type(4))) float f32x4;    // 16x16 accumulator

__device__ __forceinline__ unsigned short f2bf(float f) {
  union { float f; unsigned u; } v; v.f = f;
  unsigned r = v.u + 0x7fffu + ((v.u >> 16) & 1u);   // RNE
  return (unsigned short)(r >> 16);
}

// -------- workspace layout (bytes) --------
// [0,4096)                : group barrier counters (one per 512B — avoid false sharing)
// [4096, 4096+2*524288)   : hswz double buffer (h in A-frag swizzle, zeroed)
// [OFF_XSWZ, +64MB)       : x in A-frag swizzle (bf16); later reused for 'a' (fp32, 16MB)
// [OFF_HIST, +128MB)      : lstm_out history (bf16, [B*T][H])
#define OFF_CNT   0
#define OFF_HSWZ  4096
#define OFF_XSWZ  1052672ULL
#define OFF_HIST  68161536ULL
#define ZERO_WORDS 263168   // (4096 + 2*524288)/4

__global__ void zero_k(unsigned* __restrict__ p, int n) {
  int i = blockIdx.x * blockDim.x + threadIdx.x;
  if (i < n) p[i] = 0u;
}

// Swizzle x[b][t][k] (fp32) -> xswz[t][kc][rc][lane][8] (bf16), A-frag order.
// element: b = rc*16 + (lane&15) ; k = kc*32 + (lane>>4)*8 + j
__global__ void prep_x(const float* __restrict__ x, unsigned char* __restrict__ ws) {
  unsigned idx = blockIdx.x * 256u + threadIdx.x;   // 16384*256 = 4,194,304 exact
  int lane = idx & 63;
  int rc   = (idx >> 6) & 31;
  int kc   = (idx >> 11) & 7;
  int t    = idx >> 14;
  int b  = rc * 16 + (lane & 15);
  int k0 = kc * 32 + ((lane >> 4) & 3) * 8;
  const float* s = x + ((size_t)b * TT + t) * II + k0;
  union { unsigned short h[8]; uint4 v; } pk;
#pragma unroll
  for (int j = 0; j < 8; ++j) pk.h[j] = f2bf(s[j]);
  ((uint4*)(ws + OFF_XSWZ))[idx] = pk.v;
}

// Persistent fused LSTM. 256 blocks x 256 threads, all co-resident.
// group = blockIdx&7 (XCD-affine under round-robin), member m = blockIdx>>3.
// Group owns batch rows [group*64, +64). Member owns h-cols [m*16,+16)
// i.e. gate cols nt*512 + m*16 + [0,16) for nt = gate = 0..3 (i,f,g,o).
//
// Cross-block h exchange uses relaxed AGENT-scope 8B atomic loads/stores
// (sc0/sc1 coherent accesses — bypass per-XCD L2, served at the memory-side
// coherence point / Infinity Cache). No fences: __syncthreads() drains
// vmcnt(0) before the counter add, so publishes are visible before the
// counter increments; poller h-loads bypass caches so cannot read stale h.
__global__ __launch_bounds__(256, 1) void lstm_persist(
    const float* __restrict__ Wih, const float* __restrict__ Whh,
    const float* __restrict__ bih, const float* __restrict__ bhh,
    unsigned char* __restrict__ ws)
{
  const int gid = blockIdx.x;
  const int group = gid & 7;
  const int m = gid >> 3;
  const int tid = threadIdx.x;
  const int wv = tid >> 6, lane = tid & 63;
  const int mb = wv & 1, kh = wv >> 1;       // wave = (m-half, K-half)
  const int lq = lane >> 4, ln = lane & 15;  // quad, low nibble

  int* cnt = (int*)(ws + OFF_CNT + (size_t)group * 512);  // one line per group
  unsigned char* xswz  = ws + OFF_XSWZ;
  unsigned char* hswz0 = ws + OFF_HSWZ;
  unsigned char* hswz1 = ws + OFF_HSWZ + 524288;
  unsigned char* hist  = ws + OFF_HIST;

  // ---- W-slice preload into VGPRs: Wf[kk][nt], K-half per wave, no dup ----
  bf16x8 Wf[12][4];
#pragma unroll
  for (int kk = 0; kk < 12; ++kk) {
    const int kb = kh * 384 + kk * 32 + lq * 8;   // never straddles 256
#pragma unroll
    for (int nt = 0; nt < 4; ++nt) {
      const int gcol = nt * 512 + m * 16 + ln;
      const float* s = (kb < 256) ? (Wih + (size_t)gcol * 256 + kb)
                                  : (Whh + (size_t)gcol * 512 + (kb - 256));
      bf16x8 w;
#pragma unroll
      for (int j = 0; j < 8; ++j) w[j] = (short)f2bf(s[j]);
      Wf[kk][nt] = w;
    }
  }

  __shared__ float g_s[64 * 69];   // gate preacts [row][gate*16+jl], padded stride
  __shared__ float c_s[64 * 17];   // cell state
  __shared__ float h_s[64 * 17];   // new h (fp32 staging)
  __shared__ float bias_s[64];

  for (int i = tid; i < 64 * 17; i += 256) c_s[i] = 0.f;
  if (tid < 64) {
    int gcol = (tid >> 4) * 512 + m * 16 + (tid & 15);
    bias_s[tid] = bih[gcol] + bhh[gcol];
  }
  __syncthreads();

  const int rcb = group * 4 + mb * 2;   // row-chunk base (16-row chunks)
  const int row_cu = tid & 63;          // cell-update row
  const int jq = tid >> 6;              // cell-update jl group (4 cols)
  const f32x4 zero4 = {0.f, 0.f, 0.f, 0.f};

#pragma unroll 1
  for (int t = 0; t < 256; ++t) {
    unsigned char* hrd = (t & 1) ? hswz1 : hswz0;
    unsigned char* hwr = (t & 1) ? hswz0 : hswz1;

    f32x4 acc[2][4];
#pragma unroll
    for (int mt = 0; mt < 2; ++mt)
#pragma unroll
      for (int nt = 0; nt < 4; ++nt) acc[mt][nt] = zero4;

    // ---- K-loop: A-frags from swizzled global, W from VGPRs ----
    // x chunks: plain 16B loads (read-only, L2-cacheable).
    // h chunks: 2x 8B relaxed agent-scope atomic loads (coherent, cache-bypass).
#pragma unroll
    for (int kk = 0; kk < 12; ++kk) {
      const int kg = kh * 384 + kk * 32;
      bf16x8 a0, a1;
      if (kg < 256) {
        const unsigned char* base = xswz + (size_t)(t * 8 + (kg >> 5)) * 32768u;
        a0 = *(const bf16x8*)(base + (((rcb + 0) * 64 + lane) * 16));
        a1 = *(const bf16x8*)(base + (((rcb + 1) * 64 + lane) * 16));
      } else {
        const unsigned char* base = hrd + (size_t)((kg - 256) >> 5) * 32768u;
        const unsigned long long* p0 =
            (const unsigned long long*)(base + (((rcb + 0) * 64 + lane) * 16));
        const unsigned long long* p1 =
            (const unsigned long long*)(base + (((rcb + 1) * 64 + lane) * 16));
        union { unsigned long long q[2]; bf16x8 v; } u0, u1;
        u0.q[0] = __hip_atomic_load(p0 + 0, __ATOMIC_RELAXED, __HIP_MEMORY_SCOPE_AGENT);
        u0.q[1] = __hip_atomic_load(p0 + 1, __ATOMIC_RELAXED, __HIP_MEMORY_SCOPE_AGENT);
        u1.q[0] = __hip_atomic_load(p1 + 0, __ATOMIC_RELAXED, __HIP_MEMORY_SCOPE_AGENT);
        u1.q[1] = __hip_atomic_load(p1 + 1, __ATOMIC_RELAXED, __HIP_MEMORY_SCOPE_AGENT);
        a0 = u0.v; a1 = u1.v;
      }
#pragma unroll
      for (int nt = 0; nt < 4; ++nt) {
        acc[0][nt] = __builtin_amdgcn_mfma_f32_16x16x32_bf16(a0, Wf[kk][nt], acc[0][nt], 0, 0, 0);
        acc[1][nt] = __builtin_amdgcn_mfma_f32_16x16x32_bf16(a1, Wf[kk][nt], acc[1][nt], 0, 0, 0);
      }
    }

    // ---- split-K reduce via LDS (C/D layout: col=ln, row=lq*4+r) ----
    if (kh == 1) {
#pragma unroll
      for (int mt = 0; mt < 2; ++mt)
#pragma unroll
        for (int nt = 0; nt < 4; ++nt)
#pragma unroll
          for (int r = 0; r < 4; ++r)
            g_s[(mb * 32 + mt * 16 + lq * 4 + r) * 69 + nt * 16 + ln] = acc[mt][nt][r];
    }
    __syncthreads();
    if (kh == 0) {
#pragma unroll
      for (int mt = 0; mt < 2; ++mt)
#pragma unroll
        for (int nt = 0; nt < 4; ++nt)
#pragma unroll
          for (int r = 0; r < 4; ++r) {
            int ix = (mb * 32 + mt * 16 + lq * 4 + r) * 69 + nt * 16 + ln;
            g_s[ix] += acc[mt][nt][r];
          }
    }
    __syncthreads();

    // ---- cell update: 4 cells per thread (row, jl=jq*4+jj) ----
    {
      float hv[4];
#pragma unroll
      for (int jj = 0; jj < 4; ++jj) {
        int jl = jq * 4 + jj;
        float gi = g_s[row_cu * 69 + jl]      + bias_s[jl];
        float gf = g_s[row_cu * 69 + 16 + jl] + bias_s[16 + jl];
        float gg = g_s[row_cu * 69 + 32 + jl] + bias_s[32 + jl];
        float go = g_s[row_cu * 69 + 48 + jl] + bias_s[48 + jl];
        float iv = 1.f / (1.f + __expf(-gi));
        float fv = 1.f / (1.f + __expf(-gf));
        float gv = 1.f - 2.f / (__expf(2.f * gg) + 1.f);
        float ov = 1.f / (1.f + __expf(-go));
        float cv = fv * c_s[row_cu * 17 + jl] + iv * gv;
        c_s[row_cu * 17 + jl] = cv;
        float h = ov * (1.f - 2.f / (__expf(2.f * cv) + 1.f));
        h_s[row_cu * 17 + jl] = h;
        hv[jj] = h;
      }
      int b = group * 64 + row_cu;
      ushort4 hq = make_ushort4(f2bf(hv[0]), f2bf(hv[1]), f2bf(hv[2]), f2bf(hv[3]));
      *(ushort4*)(hist + ((size_t)(b * 256 + t) * 512 + m * 16 + jq * 4) * 2) = hq;
    }
    __syncthreads();

    // ---- publish h slice into hwr in A-frag swizzle (8B coherent store/thread) ----
    {
      int rc_l = tid >> 6;                // 0..3 (row chunk)
      int rem = tid & 63;
      int lane_off = rem >> 1;            // 0..31
      int half = rem & 1;
      int l2 = (m & 1) * 32 + lane_off;   // target lane in chunk
      int rowl = rc_l * 16 + (lane_off & 15);
      int jb = (lane_off >> 4) * 8 + half * 4;
      union { ushort4 s; unsigned long long q; } pk;
      pk.s = make_ushort4(f2bf(h_s[rowl * 17 + jb + 0]),
                          f2bf(h_s[rowl * 17 + jb + 1]),
                          f2bf(h_s[rowl * 17 + jb + 2]),
                          f2bf(h_s[rowl * 17 + jb + 3]));
      size_t off = ((size_t)((m >> 1) * 32 + group * 4 + rc_l) * 64 + l2) * 16 + half * 8;
      __hip_atomic_store((unsigned long long*)(hwr + off), pk.q,
                         __ATOMIC_RELAXED, __HIP_MEMORY_SCOPE_AGENT);
    }
    __syncthreads();   // drains vmcnt(0): all publishes at coherence point

    // ---- per-group device-scope barrier (no fences; padded counter line) ----
    if (tid == 0) {
      __hip_atomic_fetch_add(cnt, 1, __ATOMIC_RELAXED, __HIP_MEMORY_SCOPE_AGENT);
      int target = (t + 1) * 32;
      int iter = 0;
      while (__hip_atomic_load(cnt, __ATOMIC_RELAXED, __HIP_MEMORY_SCOPE_AGENT) < target
             && iter < (1 << 18)) { ++iter; __builtin_amdgcn_s_sleep(1); }
    }
    __syncthreads();
  }
}

// Epilogue 1: a[r][0..32) = lstm_hist[r][:] @ fc1_w^T   (r = b*T + t), fp32 out, no bias.
__global__ __launch_bounds__(256) void e1_fc1(
    const float* __restrict__ fc1_w, const unsigned char* __restrict__ hist,
    float* __restrict__ a_out)
{
  const int tid = threadIdx.x, wv = tid >> 6, lane = tid & 63;
  const int lq = lane >> 4, ln = lane & 15;

  bf16x8 Bf[16][2];
#pragma unroll
  for (int kk = 0; kk < 16; ++kk) {
#pragma unroll
    for (int nt = 0; nt < 2; ++nt) {
      const float* s = fc1_w + (size_t)(nt * 16 + ln) * 512 + kk * 32 + lq * 8;
      bf16x8 w;
#pragma unroll
      for (int j = 0; j < 8; ++j) w[j] = (short)f2bf(s[j]);
      Bf[kk][nt] = w;
    }
  }

  const int rbase = blockIdx.x * 128 + wv * 32;
  const f32x4 zero4 = {0.f, 0.f, 0.f, 0.f};
  f32x4 acc[2][2] = {{zero4, zero4}, {zero4, zero4}};
#pragma unroll
  for (int kk = 0; kk < 16; ++kk) {
    bf16x8 a0 = *(const bf16x8*)(hist + ((size_t)(rbase + ln) * 512 + kk * 32 + lq * 8) * 2);
    bf16x8 a1 = *(const bf16x8*)(hist + ((size_t)(rbase + 16 + ln) * 512 + kk * 32 + lq * 8) * 2);
#pragma unroll
    for (int nt = 0; nt < 2; ++nt) {
      acc[0][nt] = __builtin_amdgcn_mfma_f32_16x16x32_bf16(a0, Bf[kk][nt], acc[0][nt], 0, 0, 0);
      acc[1][nt] = __builtin_amdgcn_mfma_f32_16x16x32_bf16(a1, Bf[kk][nt], acc[1][nt], 0, 0, 0);
    }
  }
#pragma unroll
  for (int mt = 0; mt < 2; ++mt)
#pragma unroll
    for (int nt = 0; nt < 2; ++nt)
#pragma unroll
      for (int r = 0; r < 4; ++r) {
        int row = rbase + mt * 16 + lq * 4 + r;
        a_out[(size_t)row * 32 + nt * 16 + ln] = acc[mt][nt][r];
      }
}

// Epilogue 2: per-t BN1 + leaky-relu + fc2 + BN2 + relu. One block per t.
__global__ __launch_bounds__(256) void e2_head(
    const float* __restrict__ a_in, const float* __restrict__ fc1_b,
    const float* __restrict__ fc2_w, const float* __restrict__ fc2_b,
    const float* __restrict__ bn1_g, const float* __restrict__ bn1_b,
    const float* __restrict__ bn2_g, const float* __restrict__ bn2_b,
    float* __restrict__ out)
{
  const int t = blockIdx.x, tid = threadIdx.x;
  __shared__ float fb[32], fw[32];
  __shared__ float red[4][2], red2[4][2];
  if (tid < 32) { fb[tid] = fc1_b[tid]; fw[tid] = fc2_w[tid]; }
  __syncthreads();

  float va[2][32];
  float s1 = 0.f, s2 = 0.f;
#pragma unroll
  for (int rr = 0; rr < 2; ++rr) {
    int b = tid * 2 + rr;
    const float* p = a_in + ((size_t)b * 256 + t) * 32;
#pragma unroll
    for (int o = 0; o < 32; ++o) {
      float v = p[o] + fb[o];
      va[rr][o] = v;
      s1 += v; s2 += v * v;
    }
  }
#pragma unroll
  for (int off = 32; off > 0; off >>= 1) {
    s1 += __shfl_down(s1, off);
    s2 += __shfl_down(s2, off);
  }
  if ((tid & 63) == 0) { red[tid >> 6][0] = s1; red[tid >> 6][1] = s2; }
  __syncthreads();
  float tot1 = red[0][0] + red[1][0] + red[2][0] + red[3][0];
  float tot2 = red[0][1] + red[1][1] + red[2][1] + red[3][1];
  float m1 = tot1 * (1.f / 16384.f);
  float v1 = tot2 * (1.f / 16384.f) - m1 * m1;
  float sc1 = bn1_g[t] * rsqrtf(v1 + 1e-5f);
  float sh1 = bn1_b[t];

  float z[2];
  float zs1 = 0.f, zs2 = 0.f;
#pragma unroll
  for (int rr = 0; rr < 2; ++rr) {
    float acc = fc2_b[0];
#pragma unroll
    for (int o = 0; o < 32; ++o) {
      float av = (va[rr][o] - m1) * sc1 + sh1;
      av = (av > 0.f) ? av : 0.1f * av;
      acc += av * fw[o];
    }
    z[rr] = acc; zs1 += acc; zs2 += acc * acc;
  }
#pragma unroll
  for (int off = 32; off > 0; off >>= 1) {
    zs1 += __shfl_down(zs1, off);
    zs2 += __shfl_down(zs2, off);
  }
  if ((tid & 63) == 0) { red2[tid >> 6][0] = zs1; red2[tid >> 6][1] = zs2; }
  __syncthreads();
  float zt1 = red2[0][0] + red2[1][0] + red2[2][0] + red2[3][0];
  float zt2 = red2[0][1] + red2[1][1] + red2[2][1] + red2[3][1];
  float m2 = zt1 * (1.f / 512.f);
  float v2 = zt2 * (1.f / 512.f) - m2 * m2;
  float sc2 = bn2_g[t] * rsqrtf(v2 + 1e-5f);
  float sh2 = bn2_b[t];
#pragma unroll
  for (int rr = 0; rr < 2; ++rr) {
    int b = tid * 2 + rr;
    float res = (z[rr] - m2) * sc2 + sh2;
    out[(size_t)b * 256 + t] = (res > 0.f) ? res : 0.f;
  }
}

extern "C" void kernel_launch(void* const* d_in, const int* in_sizes, int n_in,
                              void* d_out, int out_size, void* d_ws, size_t ws_size,
                              hipStream_t stream) {
  const float* x    = (const float*)d_in[0];
  const float* Wih  = (const float*)d_in[1];
  const float* Whh  = (const float*)d_in[2];
  const float* bih  = (const float*)d_in[3];
  const float* bhh  = (const float*)d_in[4];
  const float* fc1w = (const float*)d_in[5];
  const float* fc1b = (const float*)d_in[6];
  const float* fc2w = (const float*)d_in[7];
  const float* fc2b = (const float*)d_in[8];
  const float* b1g  = (const float*)d_in[9];
  const float* b1b  = (const float*)d_in[10];
  const float* b2g  = (const float*)d_in[11];
  const float* b2b  = (const float*)d_in[12];
  unsigned char* ws = (unsigned char*)d_ws;
  float* out = (float*)d_out;
  float* a_buf = (float*)(ws + OFF_XSWZ);   // reuses xswz region after persist

  zero_k<<<1028, 256, 0, stream>>>((unsigned*)ws, ZERO_WORDS);
  prep_x<<<16384, 256, 0, stream>>>(x, ws);
  lstm_persist<<<256, 256, 0, stream>>>(Wih, Whh, bih, bhh, ws);
  e1_fc1<<<1024, 256, 0, stream>>>(fc1w, ws + OFF_HIST, a_buf);
  e2_head<<<256, 256, 0, stream>>>(a_buf, fc1b, fc2w, fc2b, b1g, b1b, b2g, b2b, out);
}